// Round 3
// baseline (208.746 us; speedup 1.0000x reference)
//
#include <hip/hip_runtime.h>

// LightningIndexer: out[b,q,k] = sum_h w_h * relu( (xWq^T+bq)[b,q,h,:] . (xWk^T+bk)[b,k,h,:] )
// B=2, S=4096, Dmodel=1024, H=4, HD=64.
// R7: counted-vmcnt pipeline kept, sched_barrier(0) pins REMOVED (m141:
// order-pinning defeats the scheduler; R6 regression). k_proj A-path back to
// R4's coalesced padded form (256B/row/instr float4, As[64][72]) inside the
// dbuf pipeline. Swapped-operand MFMA kept (vector stores, refcheck'd R6).

typedef __bf16 bf16;
typedef __bf16 bf16x4 __attribute__((ext_vector_type(4)));
typedef __bf16 bf16x8 __attribute__((ext_vector_type(8)));
typedef float f32x4 __attribute__((ext_vector_type(4)));

#define SEQ 4096
#define DMODEL 1024
#define NPROJ 256       // NHEAD*HDIM
#define MTOT 8192       // NB*SEQ

// async global->LDS, 16B per lane; LDS dest = wave-uniform base + lane*16
__device__ __forceinline__ void async16(const void* g, void* l) {
  __builtin_amdgcn_global_load_lds(
      (const __attribute__((address_space(1))) void*)g,
      (__attribute__((address_space(3))) void*)l, 16, 0, 0);
}

// light barrier: compiler memory fences only (no sched_barrier pinning)
#define BAR()                                    \
  do {                                           \
    asm volatile("" ::: "memory");               \
    __builtin_amdgcn_s_barrier();                \
    asm volatile("" ::: "memory");               \
  } while (0)

// ---------------- K0: convert Wq, Wk fp32 -> bf16 (2 MB total) ----------
__global__ __launch_bounds__(256) void k_convert(const float* __restrict__ wq,
                                                 const float* __restrict__ wk,
                                                 bf16* __restrict__ wqb,
                                                 bf16* __restrict__ wkb) {
  int i = blockIdx.x * 256 + threadIdx.x;  // 65536 float4 groups per matrix
  float4 a = ((const float4*)wq)[i];
  bf16x4 oa = {(bf16)a.x, (bf16)a.y, (bf16)a.z, (bf16)a.w};
  ((bf16x4*)wqb)[i] = oa;
  float4 b = ((const float4*)wk)[i];
  bf16x4 ob = {(bf16)b.x, (bf16)b.y, (bf16)b.z, (bf16)b.w};
  ((bf16x4*)wkb)[i] = ob;
}

// ---------------- K1: projection GEMM (swapped MFMA, counted pipeline) ---
// out[m,n] = sum_d x[m,d]*W[n,d] + bias[n], bf16 out.
// BM=64, BN=128, BK=64. grid (128 mtiles, 2 z, 2 nh) = 512 blocks, 2/CU.
// A (x fp32): coalesced float4 (16 lanes x 16B = 256B/row per instr),
// reg-staged cvt -> padded As[64][72] (bank-conflict-free, R4-verified).
// B (W bf16): async16 with XOR chunk swizzle.
// Per-iter VMEM ledger: [xload 4][asyncB 4]; vmcnt(8) drains asyncB(t);
// vmcnt(4) after compute drains xload(t+1). Never vmcnt(0) in the loop.
__global__ __launch_bounds__(256, 2) void k_proj(
    const float* __restrict__ x, const bf16* __restrict__ wqb,
    const bf16* __restrict__ wkb, const float* __restrict__ qbias,
    const float* __restrict__ kbias, bf16* __restrict__ Qb,
    bf16* __restrict__ Kb) {
  __shared__ __align__(16) bf16 As[2][64 * 72];    // padded, 9 KB each
  __shared__ __align__(16) bf16 Bs[2][128 * 64];   // 16 KB each (50 KB total)
  const int t = threadIdx.x;
  const int lane = t & 63, w = t >> 6;
  const int m16 = lane & 15, q = lane >> 4;
  const int m0 = blockIdx.x * 64;
  const int z = blockIdx.y;                        // 0 = Q, 1 = K
  const int nh = blockIdx.z;                       // n half
  const bf16* __restrict__ W = z ? wkb : wqb;

  const int xr = t >> 4;          // row within each 16-row group (0..15)
  const int xc = (t & 15) * 4;    // float col: 16 lanes x float4 = 64 floats

  f32x4 acc[2][4];
#pragma unroll
  for (int nt = 0; nt < 2; nt++)
#pragma unroll
    for (int mt = 0; mt < 4; mt++) acc[nt][mt] = {0.f, 0.f, 0.f, 0.f};

  float4 xv[4];
  auto xload = [&](int kt) {
#pragma unroll
    for (int p = 0; p < 4; p++)
      xv[p] = *(const float4*)(x + (size_t)(m0 + p * 16 + xr) * DMODEL +
                               kt * 64 + xc);
  };
  auto writeA = [&](int buf) {
#pragma unroll
    for (int p = 0; p < 4; p++) {
      bf16x4 o = {(bf16)xv[p].x, (bf16)xv[p].y, (bf16)xv[p].z, (bf16)xv[p].w};
      *(bf16x4*)(As[buf] + (p * 16 + xr) * 72 + xc) = o;
    }
  };
  auto stageB = [&](int buf, int kt) {
#pragma unroll
    for (int p = 0; p < 4; p++) {
      int g = w * 4 + p;                 // 8-row group, wave-uniform base
      int r = g * 8 + (lane >> 3);
      int c = (lane & 7) ^ (r & 7);      // XOR chunk swizzle (source side)
      async16(W + (size_t)(nh * 128 + r) * DMODEL + kt * 64 + c * 8,
              Bs[buf] + g * 512);
    }
  };
  auto compute = [&](int buf) {
    const bf16* As_ = As[buf];
    const bf16* Bs_ = Bs[buf];
#pragma unroll
    for (int s = 0; s < 2; s++) {
      bf16x8 af[2], bxr[4];
#pragma unroll
      for (int nt = 0; nt < 2; nt++) {
        int n = w * 32 + nt * 16 + m16;
        int cc = (s * 4 + q) ^ (n & 7);
        af[nt] = *(const bf16x8*)(Bs_ + n * 64 + cc * 8);
      }
#pragma unroll
      for (int mt = 0; mt < 4; mt++)
        bxr[mt] = *(const bf16x8*)(As_ + (mt * 16 + m16) * 72 + s * 32 + q * 8);
#pragma unroll
      for (int nt = 0; nt < 2; nt++)
#pragma unroll
        for (int mt = 0; mt < 4; mt++)
          acc[nt][mt] = __builtin_amdgcn_mfma_f32_16x16x32_bf16(
              af[nt], bxr[mt], acc[nt][mt], 0, 0, 0);
    }
  };

  // prologue: tile 0
  xload(0);
  stageB(0, 0);
  asm volatile("s_waitcnt vmcnt(4)" ::: "memory");  // xload(0) done
  writeA(0);

  for (int kt = 0; kt < 15; kt++) {
    xload(kt + 1);
    stageB((kt + 1) & 1, kt + 1);
    // outstanding: asyncB(kt)4 + xload(kt+1)4 + asyncB(kt+1)4 = 12;
    // vmcnt(8) drains asyncB(kt); lgkmcnt(0) lands this wave's As writes
    asm volatile("s_waitcnt vmcnt(8) lgkmcnt(0)" ::: "memory");
    BAR();
    compute(kt & 1);
    asm volatile("s_waitcnt vmcnt(4)" ::: "memory");  // xload(kt+1) done
    writeA((kt + 1) & 1);                             // other buffer: no race
    BAR();  // all waves done reading buf(kt) before stage(kt+2) overwrites
  }
  asm volatile("s_waitcnt vmcnt(0) lgkmcnt(0)" ::: "memory");
  BAR();
  compute(1);

  const float* __restrict__ bias = z ? kbias : qbias;
  bf16* __restrict__ outp = z ? Kb : Qb;
#pragma unroll
  for (int nt = 0; nt < 2; nt++) {
    int ncol = nh * 128 + w * 32 + nt * 16 + q * 4;  // D reg axis = n
    float4 bv = *(const float4*)(bias + ncol);
#pragma unroll
    for (int mt = 0; mt < 4; mt++) {
      int m = m0 + mt * 16 + m16;                    // D: m = lane&15
      bf16x4 o = {(bf16)(acc[nt][mt][0] + bv.x), (bf16)(acc[nt][mt][1] + bv.y),
                  (bf16)(acc[nt][mt][2] + bv.z), (bf16)(acc[nt][mt][3] + bv.w)};
      *(bf16x4*)(outp + (size_t)m * NPROJ + ncol) = o;
    }
  }
}

// ---------------- K2: scores (swapped MFMA, counted pipeline) ------------
// grid 512 (2/CU). Q strip 128 rows in regs; K range 512 rows as 8 subtiles
// of 64 rows, dbuf 2x32KB. Per-iter ledger: outstanding at wait =
// stage(st)8 + stores(st-1)8 + stage(st+1)8; vmcnt(8) drains the oldest 16
// -> stage(st) landed, old stores retired; stage(st+1) stays in flight.
// Stores retire across a full phase, never on the critical path.
// kq = bx&7 pins each 512-row K slice to one XCD's L2.
__global__ __launch_bounds__(256, 2) void k_scores(
    const bf16* __restrict__ Qb, const bf16* __restrict__ Kb,
    const float* __restrict__ iw, float* __restrict__ out) {
  __shared__ __align__(16) bf16 Ks[2][64 * 256];  // 2 x 32 KB
  const int t = threadIdx.x;
  const int lane = t & 63, w = t >> 6;
  const int m16 = lane & 15, q = lane >> 4;

  const int bx = blockIdx.x;
  const int kq = bx & 7;          // K range: kq*512 .. +511
  const int strip = bx >> 3;      // 0..63
  const int bz = strip >> 5;
  const int q0 = (strip & 31) * 128;
  const int k0 = kq * 512;

  const float whs[4] = {iw[0], iw[1], iw[2], iw[3]};

  // Q strip fragments (MFMA B operand) to registers, once per block
  bf16x8 aq[2][4][2];
  {
    const bf16* qp =
        Qb + (size_t)(bz * SEQ + q0 + w * 32 + m16) * NPROJ + q * 8;
#pragma unroll
    for (int qt = 0; qt < 2; qt++)
#pragma unroll
      for (int h = 0; h < 4; h++)
#pragma unroll
        for (int j = 0; j < 2; j++)
          aq[qt][h][j] = *(const bf16x8*)(qp + (size_t)qt * 16 * NPROJ +
                                          h * 64 + j * 32);
  }

  auto stage = [&](int buf, int st) {
    // 64 rows x 512B = 32 KB = 32 calls (8/wave), 2 rows/call
#pragma unroll
    for (int p = 0; p < 8; p++) {
      int g = w * 8 + p;
      int r = g * 2 + (lane >> 5);
      int c = (lane & 31) ^ (r & 31);           // XOR chunk swizzle
      async16(Kb + ((size_t)bz * SEQ + k0 + st * 64 + r) * NPROJ + c * 8,
              Ks[buf] + g * 512);
    }
  };

  // prologue: subtile 0 staged and drained once (aq loads drain here too)
  stage(0, 0);
  asm volatile("s_waitcnt vmcnt(0)" ::: "memory");
  BAR();

  for (int st = 0; st < 8; st++) {
    if (st < 7) stage((st + 1) & 1, st + 1);
    asm volatile("s_waitcnt vmcnt(8)" ::: "memory");
    BAR();

    const bf16* KsB = Ks[st & 1];
    f32x4 accf[4][2];
#pragma unroll
    for (int kt = 0; kt < 4; kt++)
#pragma unroll
      for (int qt = 0; qt < 2; qt++) accf[kt][qt] = {0.f, 0.f, 0.f, 0.f};

#pragma unroll
    for (int h = 0; h < 4; h++) {
      const float wh = whs[h];
      bf16x8 ak[4][2];
#pragma unroll
      for (int kt = 0; kt < 4; kt++) {
        int r = kt * 16 + m16;
        const bf16* kp = KsB + r * 256;
        int c0 = (h * 8 + q) ^ (r & 31);
        int c1 = (h * 8 + 4 + q) ^ (r & 31);
        ak[kt][0] = *(const bf16x8*)(kp + c0 * 8);
        ak[kt][1] = *(const bf16x8*)(kp + c1 * 8);
      }
#pragma unroll
      for (int kt = 0; kt < 4; kt++)
#pragma unroll
        for (int qt = 0; qt < 2; qt++) {
          f32x4 tacc = {0.f, 0.f, 0.f, 0.f};
          tacc = __builtin_amdgcn_mfma_f32_16x16x32_bf16(ak[kt][0],
                                                         aq[qt][h][0], tacc,
                                                         0, 0, 0);
          tacc = __builtin_amdgcn_mfma_f32_16x16x32_bf16(ak[kt][1],
                                                         aq[qt][h][1], tacc,
                                                         0, 0, 0);
#pragma unroll
          for (int e = 0; e < 4; e++)
            accf[kt][qt][e] += wh * fmaxf(tacc[e], 0.f);
        }
    }

    BAR();  // all waves done reading buf (st&1) before next stage hits it

    // stores after the barrier: register-only inputs, retire across the
    // next phase (drained by vmcnt(8) one iteration later, never to 0)
#pragma unroll
    for (int qt = 0; qt < 2; qt++) {
      size_t rb = ((size_t)bz * SEQ + q0 + w * 32 + qt * 16 + m16) * SEQ;
#pragma unroll
      for (int kt = 0; kt < 4; kt++) {
        int col = k0 + st * 64 + kt * 16 + q * 4;   // D reg axis = k
        *(f32x4*)(out + rb + col) = accf[kt][qt];
      }
    }
  }
}

extern "C" void kernel_launch(void* const* d_in, const int* in_sizes, int n_in,
                              void* d_out, int out_size, void* d_ws, size_t ws_size,
                              hipStream_t stream) {
  const float* x  = (const float*)d_in[0];   // [2,4096,1024]
  const float* wq = (const float*)d_in[1];   // [256,1024]
  const float* qb = (const float*)d_in[2];   // [256]
  const float* wk = (const float*)d_in[3];   // [256,1024]
  const float* kb = (const float*)d_in[4];   // [256]
  const float* iw = (const float*)d_in[5];   // [4]
  float* out = (float*)d_out;                // [2,4096,4096]

  // workspace layout (9,437,184 B total)
  char* ws = (char*)d_ws;
  bf16* wqb = (bf16*)ws;                               // 512 KB
  bf16* wkb = (bf16*)(ws + 524288);                    // 512 KB
  bf16* Qb  = (bf16*)(ws + 1048576);                   // 4 MB  [8192][256]
  bf16* Kb  = (bf16*)(ws + 1048576 + 4194304);         // 4 MB  [8192][256]

  k_convert<<<256, 256, 0, stream>>>(wq, wk, wqb, wkb);
  k_proj<<<dim3(128, 2, 2), 256, 0, stream>>>(x, wqb, wkb, qb, kb, Qb, Kb);
  k_scores<<<512, 256, 0, stream>>>(Qb, Kb, iw, out);
}

// Round 5
// 195.877 us; speedup vs baseline: 1.0657x; 1.0657x over previous
//
#include <hip/hip_runtime.h>

// LightningIndexer: out[b,q,k] = sum_h w_h * relu( (xWq^T+bq)[b,q,h,:] . (xWk^T+bk)[b,k,h,:] )
// B=2, S=4096, Dmodel=1024, H=4, HD=64.
// R8 = revert to R4 (best measured: 195.8/196.4 us). Post-R5..R7 analysis:
// dur_us = ~160us harness poison-fills (2 x 80us, irreducible) + kernels.
// R4 kernels = 36.4us vs composed memory floor ~35-39us (out-store 21us +
// proj ~10us + convert 2us + launch ~4us) -> already AT floor. The finer
// pipelines (R5-R7) added barrier/drain overhead (32 MFMA/drain vs R4's
// 128) and regressed; stores/staging were never the critical path.
// (R9 = identical resubmit; R8 bench run died to a container-acquire
// infra failure, no counters produced.)

typedef __bf16 bf16;
typedef __bf16 bf16x4 __attribute__((ext_vector_type(4)));
typedef __bf16 bf16x8 __attribute__((ext_vector_type(8)));
typedef float f32x4 __attribute__((ext_vector_type(4)));

#define NB 2
#define SEQ 4096
#define DMODEL 1024
#define NHEAD 4
#define HDIM 64
#define NPROJ 256       // NHEAD*HDIM
#define MTOT 8192       // NB*SEQ

// async global->LDS, 16B per lane; LDS dest = wave-uniform base + lane*16
__device__ __forceinline__ void async16(const void* g, void* l) {
  __builtin_amdgcn_global_load_lds(
      (const __attribute__((address_space(1))) void*)g,
      (__attribute__((address_space(3))) void*)l, 16, 0, 0);
}

// ---------------- K0: convert Wq, Wk fp32 -> bf16 ----------------
__global__ __launch_bounds__(256) void k_convert(const float* __restrict__ wq,
                                                 const float* __restrict__ wk,
                                                 bf16* __restrict__ wqb,
                                                 bf16* __restrict__ wkb) {
  int i = blockIdx.x * 256 + threadIdx.x;  // 65536 float4 groups
  float4 a = ((const float4*)wq)[i];
  bf16x4 oa = {(bf16)a.x, (bf16)a.y, (bf16)a.z, (bf16)a.w};
  ((bf16x4*)wqb)[i] = oa;
  float4 b = ((const float4*)wk)[i];
  bf16x4 ob = {(bf16)b.x, (bf16)b.y, (bf16)b.z, (bf16)b.w};
  ((bf16x4*)wkb)[i] = ob;
}

// ---------------- K1: projection GEMM ----------------
// out[m,n] = sum_k x[m,k]*W[n,k] + bias[n], stored bf16.
// BM=64, BN=128, BK=64. grid (128 mtiles, 2 z, 2 nhalf) = 512 blocks, 2/CU.
__global__ __launch_bounds__(256, 4) void k_proj(
    const float* __restrict__ x, const bf16* __restrict__ wqb,
    const bf16* __restrict__ wkb, const float* __restrict__ qbias,
    const float* __restrict__ kbias, bf16* __restrict__ Qb,
    bf16* __restrict__ Kb) {
  __shared__ __align__(16) bf16 As[64 * 72];   // padded rows
  __shared__ __align__(16) bf16 Bs[128 * 64];  // async16, XOR chunk swizzle
  const int t = threadIdx.x;
  const int lane = t & 63, w = t >> 6;
  const int m16 = lane & 15, q = lane >> 4;
  const int m0 = blockIdx.x * 64;
  const int z = blockIdx.y;
  const int nh = blockIdx.z;                   // n half: cols nh*128..+127
  const bf16* __restrict__ W = z ? wkb : wqb;

  f32x4 acc[4][2];
#pragma unroll
  for (int i = 0; i < 4; i++)
#pragma unroll
    for (int j = 0; j < 2; j++) acc[i][j] = {0.f, 0.f, 0.f, 0.f};

  for (int kt = 0; kt < 16; kt++) {
#pragma unroll
    for (int p = 0; p < 4; p++) {
      int n0 = w * 32 + p * 8;                 // wave-uniform base
      int r = n0 + (lane >> 3);
      int c = (lane & 7) ^ (r & 7);            // swizzled source chunk
      async16(W + (size_t)(nh * 128 + r) * DMODEL + kt * 64 + c * 8,
              Bs + n0 * 64);
    }
#pragma unroll
    for (int p = 0; p < 4; p++) {
      int r = p * 16 + (t >> 4);
      int c = (t & 15) * 4;
      float4 v = *(const float4*)(x + (size_t)(m0 + r) * DMODEL + kt * 64 + c);
      bf16x4 o = {(bf16)v.x, (bf16)v.y, (bf16)v.z, (bf16)v.w};
      *(bf16x4*)(As + r * 72 + c) = o;
    }
    __builtin_amdgcn_s_waitcnt(0);
    __syncthreads();

#pragma unroll
    for (int s = 0; s < 2; s++) {
      bf16x8 a[4], b[2];
#pragma unroll
      for (int mt = 0; mt < 4; mt++)
        a[mt] = *(const bf16x8*)(As + (mt * 16 + m16) * 72 + s * 32 + q * 8);
#pragma unroll
      for (int nt = 0; nt < 2; nt++) {
        int n = w * 32 + nt * 16 + m16;
        int cc = (4 * s + q) ^ (n & 7);
        b[nt] = *(const bf16x8*)(Bs + n * 64 + cc * 8);
      }
#pragma unroll
      for (int mt = 0; mt < 4; mt++)
#pragma unroll
        for (int nt = 0; nt < 2; nt++)
          acc[mt][nt] = __builtin_amdgcn_mfma_f32_16x16x32_bf16(
              a[mt], b[nt], acc[mt][nt], 0, 0, 0);
    }
    __syncthreads();
  }

  const float* __restrict__ bias = z ? kbias : qbias;
  bf16* __restrict__ outp = z ? Kb : Qb;
#pragma unroll
  for (int nt = 0; nt < 2; nt++) {
    int col = nh * 128 + w * 32 + nt * 16 + m16;  // C/D: col = lane&15
    float bv = bias[col];
#pragma unroll
    for (int mt = 0; mt < 4; mt++) {
      int row0 = m0 + mt * 16 + q * 4;            // C/D: row = quad*4 + reg
#pragma unroll
      for (int e = 0; e < 4; e++)
        outp[(size_t)(row0 + e) * NPROJ + col] = (bf16)(acc[mt][nt][e] + bv);
    }
  }
}

// ---------------- K2: scores ----------------
// grid 512 blocks (= 2/CU exactly). Block: Q strip of 128 rows (bz, q0) held
// in registers (all 4 heads); loops 4 K-tiles (kq*4+i). Per tile: stage
// K[128 rows][256 cols] = 64KB LDS (XOR chunk swizzle, 2 rows per async16
// call), then per wave: 4 heads x 2 mt x 8 nt x 2-chain MFMA (128 MFMA per
// drain), fold w_h*relu, store 32x128 chunk. LDS row = 512B; b-frag slot
// = (h*8+j*4+q) ^ (n&31) -> banks covered 2x (free).
__global__ __launch_bounds__(256, 2) void k_scores(
    const bf16* __restrict__ Qb, const bf16* __restrict__ Kb,
    const float* __restrict__ iw, float* __restrict__ out) {
  __shared__ __align__(16) bf16 Ks[128 * 256];  // 64 KB
  const int t = threadIdx.x;
  const int lane = t & 63, w = t >> 6;
  const int m16 = lane & 15, q = lane >> 4;

  const int bx = blockIdx.x;
  const int kq = bx & 7;          // K-tile group: tiles kq*4 .. kq*4+3
  const int strip = bx >> 3;      // 0..63
  const int bz = strip >> 5;
  const int q0 = (strip & 31) * 128;

  const float wh0 = iw[0], wh1 = iw[1], wh2 = iw[2], wh3 = iw[3];
  const float whs[4] = {wh0, wh1, wh2, wh3};

  // ---- load Q strip fragments to registers (once) ----
  // wave w owns rows q0 + w*32 + mt*16 + m16; k = h*64 + j*32 + q*8
  bf16x8 aq[2][4][2];
  {
    const bf16* qp =
        Qb + (size_t)(bz * SEQ + q0 + w * 32 + m16) * NPROJ + q * 8;
#pragma unroll
    for (int mt = 0; mt < 2; mt++)
#pragma unroll
      for (int h = 0; h < 4; h++)
#pragma unroll
        for (int j = 0; j < 2; j++)
          aq[mt][h][j] =
              *(const bf16x8*)(qp + (size_t)mt * 16 * NPROJ + h * 64 + j * 32);
  }

  for (int i = 0; i < 4; i++) {
    const int kx = kq * 4 + i;
    const size_t kbase = ((size_t)bz * SEQ + (size_t)kx * 128) * NPROJ;
    __syncthreads();  // prev-iter LDS reads complete before overwrite
    // stage K tile: 64 calls (16/wave), each stages 2 rows (1 KB)
#pragma unroll
    for (int p = 0; p < 16; p++) {
      int g = w * 16 + p;                 // 2-row group, wave-uniform
      int r = g * 2 + (lane >> 5);
      int c = (lane & 31) ^ (r & 31);     // XOR chunk swizzle
      async16(Kb + kbase + (size_t)r * NPROJ + c * 8, Ks + g * 512);
    }
    __builtin_amdgcn_s_waitcnt(0);
    __syncthreads();

    f32x4 accf[2][8];
#pragma unroll
    for (int mt = 0; mt < 2; mt++)
#pragma unroll
      for (int nt = 0; nt < 8; nt++) accf[mt][nt] = {0.f, 0.f, 0.f, 0.f};

#pragma unroll
    for (int h = 0; h < 4; h++) {
      const float wh = whs[h];
      bf16x8 bk[8][2];
#pragma unroll
      for (int nt = 0; nt < 8; nt++) {
        int n = nt * 16 + m16;
        const bf16* kb_ = Ks + (size_t)n * 256;
        int c0 = (h * 8 + q) ^ (n & 31);
        int c1 = (h * 8 + 4 + q) ^ (n & 31);
        bk[nt][0] = *(const bf16x8*)(kb_ + c0 * 8);
        bk[nt][1] = *(const bf16x8*)(kb_ + c1 * 8);
      }
#pragma unroll
      for (int mt = 0; mt < 2; mt++)
#pragma unroll
        for (int nt = 0; nt < 8; nt++) {
          f32x4 tacc = {0.f, 0.f, 0.f, 0.f};
          tacc = __builtin_amdgcn_mfma_f32_16x16x32_bf16(aq[mt][h][0], bk[nt][0],
                                                         tacc, 0, 0, 0);
          tacc = __builtin_amdgcn_mfma_f32_16x16x32_bf16(aq[mt][h][1], bk[nt][1],
                                                         tacc, 0, 0, 0);
#pragma unroll
          for (int e = 0; e < 4; e++)
            accf[mt][nt][e] += wh * fmaxf(tacc[e], 0.f);
        }
    }

    // store 32x128 chunk per wave (rows w*32.., cols kx*128..)
#pragma unroll
    for (int mt = 0; mt < 2; mt++)
#pragma unroll
      for (int e = 0; e < 4; e++) {
        int r = q0 + w * 32 + mt * 16 + q * 4 + e;
        size_t ob = ((size_t)bz * SEQ + r) * SEQ + (size_t)kx * 128;
#pragma unroll
        for (int nt = 0; nt < 8; nt++)
          out[ob + nt * 16 + m16] = accf[mt][nt][e];
      }
  }
}

extern "C" void kernel_launch(void* const* d_in, const int* in_sizes, int n_in,
                              void* d_out, int out_size, void* d_ws, size_t ws_size,
                              hipStream_t stream) {
  const float* x  = (const float*)d_in[0];   // [2,4096,1024]
  const float* wq = (const float*)d_in[1];   // [256,1024]
  const float* qb = (const float*)d_in[2];   // [256]
  const float* wk = (const float*)d_in[3];   // [256,1024]
  const float* kb = (const float*)d_in[4];   // [256]
  const float* iw = (const float*)d_in[5];   // [4]
  float* out = (float*)d_out;                // [2,4096,4096]

  // workspace layout (9,437,184 B total)
  char* ws = (char*)d_ws;
  bf16* wqb = (bf16*)ws;                               // 512 KB
  bf16* wkb = (bf16*)(ws + 524288);                    // 512 KB
  bf16* Qb  = (bf16*)(ws + 1048576);                   // 4 MB  [8192][256]
  bf16* Kb  = (bf16*)(ws + 1048576 + 4194304);         // 4 MB  [8192][256]

  k_convert<<<256, 256, 0, stream>>>(wq, wk, wqb, wkb);
  k_proj<<<dim3(128, 2, 2), 256, 0, stream>>>(x, wqb, wkb, qb, kb, Qb, Kb);
  k_scores<<<512, 256, 0, stream>>>(Qb, Kb, iw, out);
}